// Round 2
// baseline (8359.019 us; speedup 1.0000x reference)
//
#include <hip/hip_runtime.h>

#define NV 8192
#define NC 4096
#define NN (NV + NC)          // 12288 nodes per batch row
#define BATCH 256
#define TOT (BATCH * NN)      // 3,145,728 flat nodes
#define NEDGE 16777216
#define NITER 10

// Write x0 = concat(llr, zeros) into x. One float4 per thread.
__global__ __launch_bounds__(256) void k_init(const float* __restrict__ llr,
                                              float* __restrict__ x) {
    int base = (blockIdx.x * 256 + threadIdx.x) * 4;
    if (base >= TOT) return;
    int b = base / NN;
    int n = base - b * NN;                 // NN % 4 == 0 so n % 4 == 0
    float4 v = make_float4(0.f, 0.f, 0.f, 0.f);
    if (n < NV) v = *reinterpret_cast<const float4*>(llr + (size_t)b * NV + n);
    *reinterpret_cast<float4*>(x + base) = v;
}

// Per-edge message computation + scatter-add into xout (pre-initialized to x0).
__global__ __launch_bounds__(256) void k_edges(
    const int* __restrict__ src, const int* __restrict__ dst,
    const float* __restrict__ cm,
    const float* __restrict__ xin, float* __restrict__ xout,
    const float* __restrict__ attW, const float* __restrict__ attb,
    const float* __restrict__ scal, const float* __restrict__ pen, int it)
{
    const float W0 = attW[it * 3 + 0];
    const float W1 = attW[it * 3 + 1];
    const float W2 = attW[it * 3 + 2];
    const float bb = attb[it];
    const float sc = scal[it];
    const float pe = pen[it];

    int e = (blockIdx.x * 256 + threadIdx.x) * 4;   // NEDGE % 1024 == 0, no tail
    int4  s4 = *reinterpret_cast<const int4*>(src + e);
    int4  d4 = *reinterpret_cast<const int4*>(dst + e);
    float4 c4 = *reinterpret_cast<const float4*>(cm + e);

    int   si[4] = {s4.x, s4.y, s4.z, s4.w};
    int   di[4] = {d4.x, d4.y, d4.z, d4.w};
    float cc[4] = {c4.x, c4.y, c4.z, c4.w};

#pragma unroll
    for (int k = 0; k < 4; ++k) {
        float xs = xin[si[k]];
        float xd = xin[di[k]];
        float raw = fmaf(xs, W0, fmaf(xd, W1, fmaf(cc[k], W2, bb)));
        raw = (raw >= 0.f) ? raw : 0.01f * raw;      // leaky_relu
        raw = fmaf(cc[k], pe, raw);                  // + cycle_mask * penalty
        float sig = 1.0f / (1.0f + __expf(-raw));
        atomicAdd(xout + di[k], xs * sig * sc);
    }
}

// Emit output slice from xnew and re-init the other buffer to x0 for next iter.
__global__ __launch_bounds__(256) void k_emit_init(
    const float* __restrict__ xnew, const float* __restrict__ llr,
    float* __restrict__ xother, float* __restrict__ out, int it)
{
    int base = (blockIdx.x * 256 + threadIdx.x) * 4;
    if (base >= TOT) return;
    int b = base / NN;
    int n = base - b * NN;
    if (n < NV) {
        float4 v = *reinterpret_cast<const float4*>(xnew + base);
        *reinterpret_cast<float4*>(out + (size_t)it * (BATCH * NV) + (size_t)b * NV + n) = v;
        *reinterpret_cast<float4*>(xother + base) =
            *reinterpret_cast<const float4*>(llr + (size_t)b * NV + n);
    } else {
        *reinterpret_cast<float4*>(xother + base) = make_float4(0.f, 0.f, 0.f, 0.f);
    }
}

extern "C" void kernel_launch(void* const* d_in, const int* in_sizes, int n_in,
                              void* d_out, int out_size, void* d_ws, size_t ws_size,
                              hipStream_t stream) {
    const float* llr  = (const float*)d_in[0];
    const int*   ei   = (const int*)d_in[1];
    const float* cm   = (const float*)d_in[2];
    const float* attW = (const float*)d_in[3];
    const float* attb = (const float*)d_in[4];
    const float* scal = (const float*)d_in[5];
    const float* pen  = (const float*)d_in[6];
    float* out = (float*)d_out;

    float* xA = (float*)d_ws;          // current x
    float* xB = xA + TOT;              // scatter target (pre-set to x0)
    const int* src = ei;
    const int* dst = ei + NEDGE;

    dim3 blk(256);
    dim3 gNode(TOT / 4 / 256);     // 3072 blocks
    dim3 gEdge(NEDGE / 4 / 256);   // 16384 blocks

    k_init<<<gNode, blk, 0, stream>>>(llr, xA);
    k_init<<<gNode, blk, 0, stream>>>(llr, xB);

    for (int it = 0; it < NITER; ++it) {
        k_edges<<<gEdge, blk, 0, stream>>>(src, dst, cm, xA, xB, attW, attb, scal, pen, it);
        // write out x_new[:, :NV]; re-init xA (old source) to x0 for next iteration
        k_emit_init<<<gNode, blk, 0, stream>>>(xB, llr, xA, out, it);
        float* t = xA; xA = xB; xB = t;
    }
}